// Round 9
// baseline (989.301 us; speedup 1.0000x reference)
//
#include <hip/hip_runtime.h>
#include <hip/hip_bf16.h>
#include <math.h>

#define N_NODES 50000
#define N_EDGES 800000
#define N_GRAPHS 256
#define DIM 64
#define EDIM 50
#define HDIM 128
#define NLAYER 4
#define ZDIM (2 * DIM + EDIM)  // 178
#define NTILES (N_EDGES / 32)  // 25000

typedef __attribute__((ext_vector_type(8))) short short8v;
typedef __attribute__((ext_vector_type(16))) float f32x16;

__device__ __forceinline__ float softplus_f(float x) {
    return fmaxf(x, 0.0f) + log1pf(__expf(-fabsf(x)));
}
__device__ __forceinline__ float sig_f(float p) {
    float e = __expf(-fabsf(p));
    float r = __builtin_amdgcn_rcpf(1.0f + e);
    return (p >= 0.0f) ? r : e * r;
}
__device__ __forceinline__ float sp_f(float p) {
    float e = __expf(-fabsf(p));
    return fmaxf(p, 0.0f) + __logf(1.0f + e);
}

__device__ __forceinline__ short cvt_bf16(float f) {
    __hip_bfloat16 h = __float2bfloat16(f);
    return *reinterpret_cast<short*>(&h);
}

// Weight tiles, interleaved column layout: colv = 2*d + g (g: 0=sigmoid/Wf, 1=softplus/Ws)
// wcat[l][k][colv] = (k<50) ? W_g[l][128+k][d] : 0   (k padded to 64)
__global__ void k_wcat(const float* __restrict__ Wf, const float* __restrict__ Ws,
                       short* __restrict__ wcat) {
    int i = blockIdx.x * 256 + threadIdx.x;  // 4*64*128 = 32768
    int l = i >> 13;
    int rem = i & 8191;
    int k = rem >> 7;
    int colv = rem & 127;
    int d = colv >> 1, g = colv & 1;
    float v = 0.0f;
    if (k < 50) {
        const float* W = g ? Ws : Wf;
        v = W[((size_t)l * ZDIM + 128 + k) * 64 + d];
    }
    wcat[i] = cvt_bf16(v);
}

// ---------------- dst-sort (counting sort) ----------------
__global__ void k_hist(const int* __restrict__ eidx, int* __restrict__ hist) {
    int e = blockIdx.x * 256 + threadIdx.x;  // E exact
    atomicAdd(&hist[eidx[N_EDGES + e]], 1);
}

__global__ __launch_bounds__(256) void k_scan1(const int* __restrict__ hist,
                                               int* __restrict__ scanbuf,
                                               int* __restrict__ blocksums) {
    int tid = threadIdx.x;
    int i = blockIdx.x * 256 + tid;
    int v = (i < N_NODES) ? hist[i] : 0;
    int lane = tid & 63;
#pragma unroll
    for (int off = 1; off < 64; off <<= 1) {
        int u = __shfl_up(v, off);
        if (lane >= off) v += u;
    }
    __shared__ int wsum[4];
    if (lane == 63) wsum[tid >> 6] = v;
    __syncthreads();
    int w = tid >> 6;
    int add = 0;
#pragma unroll
    for (int k = 0; k < 3; ++k)
        if (k < w) add += wsum[k];
    v += add;
    if (i < N_NODES) scanbuf[i] = v;
    if (tid == 255) blocksums[blockIdx.x] = v;
}

__global__ __launch_bounds__(256) void k_scan2(int* __restrict__ blocksums, int nb) {
    int tid = threadIdx.x;
    int v = (tid < nb) ? blocksums[tid] : 0;
    int lane = tid & 63;
#pragma unroll
    for (int off = 1; off < 64; off <<= 1) {
        int u = __shfl_up(v, off);
        if (lane >= off) v += u;
    }
    __shared__ int wsum[4];
    if (lane == 63) wsum[tid >> 6] = v;
    __syncthreads();
    int w = tid >> 6;
    int add = 0;
#pragma unroll
    for (int k = 0; k < 3; ++k)
        if (k < w) add += wsum[k];
    v += add;
    if (tid < nb) blocksums[tid] = v;
}

__global__ void k_scan3(const int* __restrict__ scanbuf, const int* __restrict__ hist,
                        const int* __restrict__ blocksums, int* __restrict__ cursor) {
    int i = blockIdx.x * 256 + threadIdx.x;
    if (i >= N_NODES) return;
    int b = blockIdx.x;
    int off = b ? blocksums[b - 1] : 0;
    cursor[i] = scanbuf[i] - hist[i] + off;
}

__global__ void k_scatter(const int* __restrict__ eidx, int* __restrict__ cursor,
                          int* __restrict__ perm, int* __restrict__ permSrc,
                          int* __restrict__ permDst) {
    int e = blockIdx.x * 256 + threadIdx.x;
    int d = eidx[N_EDGES + e];
    int pos = atomicAdd(&cursor[d], 1);
    perm[pos] = e;
    permDst[pos] = d;
    permSrc[pos] = eidx[e];
}

// Sorted pack: thread = (tile, lane); handles all 4 kk fragments.
__global__ __launch_bounds__(256) void k_eprep2(const float* __restrict__ eattr,
                                                const int* __restrict__ perm,
                                                short* __restrict__ eattrP) {
    int i = blockIdx.x * 256 + threadIdx.x;  // over NTILES*64 = 1.6M
    int lane = i & 63;
    int tile = i >> 6;
    int pos = tile * 32 + (lane & 31);
    int h2 = lane >> 5;
    int edge = perm[pos];
    const float* erow = eattr + (size_t)edge * EDIM;  // 8B-aligned (200*edge)
    int k0 = 8 * h2;
    float2 v[12];
#pragma unroll
    for (int kk = 0; kk < 3; ++kk) {
#pragma unroll
        for (int p = 0; p < 4; ++p) {
            v[kk * 4 + p] = *(const float2*)(erow + k0 + 16 * kk + 2 * p);
        }
    }
    float2 t48 = make_float2(0.0f, 0.0f);
    if (h2 == 0) t48 = *(const float2*)(erow + 48);

    size_t fb = ((size_t)tile * 4) * 64 + lane;
#pragma unroll
    for (int kk = 0; kk < 3; ++kk) {
        short8v o;
#pragma unroll
        for (int p = 0; p < 4; ++p) {
            o[2 * p] = cvt_bf16(v[kk * 4 + p].x);
            o[2 * p + 1] = cvt_bf16(v[kk * 4 + p].y);
        }
        *(short8v*)&eattrP[(fb + (size_t)kk * 64) * 8] = o;
    }
    short8v o;
#pragma unroll
    for (int e = 0; e < 8; ++e) o[e] = 0;
    o[0] = cvt_bf16(t48.x);
    o[1] = cvt_bf16(t48.y);
    *(short8v*)&eattrP[(fb + 3 * 64) * 8] = o;
}

// Node-side matmuls, output layout [n][colv], colv = 2*d+g.
// MODE 0: read h.  MODE 1: v=softplus(h+agg), write h, zero agg (fused update).
// MODE 2: v=emb[x[n]], write h (fused embed).
template <int MODE>
__global__ __launch_bounds__(256) void k_nodemm(
    const float* __restrict__ hin, float* __restrict__ hout, float* __restrict__ agg,
    const int* __restrict__ x, const float* __restrict__ emb,
    const float* __restrict__ Wf, const float* __restrict__ bf,
    const float* __restrict__ Ws, const float* __restrict__ bs,
    float* __restrict__ dstpack, float* __restrict__ srcpack) {
    __shared__ float hs[64 * 68];
    int tid = threadIdx.x;
    int w = tid >> 6, lane = tid & 63;
    int n0 = blockIdx.x * 64;
    for (int idx = tid; idx < 64 * 64; idx += 256) {
        int i = idx >> 6, k = idx & 63;
        int n = n0 + i;
        float v = 0.0f;
        if (n < N_NODES) {
            if (MODE == 0) {
                v = hin[(size_t)n * DIM + k];
            } else if (MODE == 1) {
                v = softplus_f(hin[(size_t)n * DIM + k] + agg[(size_t)n * DIM + k]);
                agg[(size_t)n * DIM + k] = 0.0f;
                hout[(size_t)n * DIM + k] = v;
            } else {
                v = emb[x[n] * DIM + k];
                hout[(size_t)n * DIM + k] = v;
            }
        }
        hs[i * 68 + k] = v;
    }
    __syncthreads();
    int colv = (w & 1) * 64 + lane;  // 0..127 (contiguous 256B wave stores)
    int d = colv >> 1, g = colv & 1;
    const float* Wsel = g ? Ws : Wf;
    int row0 = (w < 2) ? 0 : 64;
    float wcol[64];
#pragma unroll
    for (int k = 0; k < 64; ++k) wcol[k] = Wsel[(row0 + k) * 64 + d];
    float bias = (w < 2) ? (g ? bs[d] : bf[d]) : 0.0f;
    float* outp = (w < 2) ? dstpack : srcpack;
    int nmax = min(64, N_NODES - n0);
    for (int i = 0; i < nmax; ++i) {
        float acc = bias;
#pragma unroll
        for (int k = 0; k < 64; k += 4) {
            float4 hv = *(const float4*)&hs[i * 68 + k];
            acc += hv.x * wcol[k] + hv.y * wcol[k + 1] + hv.z * wcol[k + 2] + hv.w * wcol[k + 3];
        }
        outp[(size_t)(n0 + i) * 128 + colv] = acc;
    }
}

// ---------------- sorted edge kernel: transposed MFMA + wave-private reduction ----------------
// acc = mfma(W-frag, eattr-frag): lane owns ONE edge (c = lane&31).
// Interleaved colv = 2d+g: acc[4q+{0,1,2,3}] = (d0: sig,sp), (d0+1: sig,sp)
// -> lane multiplies gates locally; wave w owns d in [16w, 16w+16): NO __syncthreads.
__global__ __launch_bounds__(256) void k_edge_s(
    const int* __restrict__ permSrc, const int* __restrict__ permDst,
    const short* __restrict__ eattrP, const float* __restrict__ dstpack,
    const float* __restrict__ srcpack, const short* __restrict__ wcat_l,
    float* __restrict__ agg) {
    __shared__ float msgM[4][16][36];  // [wave][dd][edge], pitch 36 (16B-aligned rows)
    __shared__ int dsh[4][32];         // per-wave dst indices
    int tid = threadIdx.x;
    int w = tid >> 6;
    int lane = tid & 63;
    int c = lane & 31;   // edge within tile
    int h2 = lane >> 5;

    // Weight A-fragments: wfr[kk][j] = wcat[kk*16 + 8*h2 + j][w*32 + c]
    short8v wfr[4];
#pragma unroll
    for (int kk = 0; kk < 4; ++kk) {
#pragma unroll
        for (int e = 0; e < 8; ++e) {
            wfr[kk][e] = wcat_l[(kk * 16 + 8 * h2 + e) * 128 + w * 32 + c];
        }
    }

    for (int tile = blockIdx.x; tile < NTILES; tile += gridDim.x) {
        int e0 = tile * 32;
        int myedge = e0 + c;
        int tI = permDst[myedge];
        int sI = permSrc[myedge];
        if (lane < 32) dsh[w][lane] = tI;  // lanes 0..31: c == lane

        short8v efr[4];
#pragma unroll
        for (int kk = 0; kk < 4; ++kk) {
            efr[kk] = *(const short8v*)&eattrP[(((size_t)tile * 4 + kk) * 64 + lane) * 8];
        }

        f32x16 acc;
#pragma unroll
        for (int i = 0; i < 16; ++i) acc[i] = 0.0f;
#pragma unroll
        for (int kk = 0; kk < 4; ++kk) {
            acc = __builtin_amdgcn_mfma_f32_32x32x16_bf16(wfr[kk], efr[kk], acc, 0, 0, 0);
        }

        // Gathers: colv run = w*32 + 4*h2 + 8*q + i
        const float* drow = dstpack + (((size_t)(unsigned)tI) << 7) + w * 32 + 4 * h2;
        const float* srow = srcpack + (((size_t)(unsigned)sI) << 7) + w * 32 + 4 * h2;
        float4 dv[4], sv[4];
#pragma unroll
        for (int q = 0; q < 4; ++q) dv[q] = *(const float4*)(drow + 8 * q);
#pragma unroll
        for (int q = 0; q < 4; ++q) sv[q] = *(const float4*)(srow + 8 * q);

        // local gate pairing: dd = 4q + 2h2 (+1)
#pragma unroll
        for (int q = 0; q < 4; ++q) {
            float p0 = acc[4 * q + 0] + dv[q].x + sv[q].x;
            float p1 = acc[4 * q + 1] + dv[q].y + sv[q].y;
            float p2 = acc[4 * q + 2] + dv[q].z + sv[q].z;
            float p3 = acc[4 * q + 3] + dv[q].w + sv[q].w;
            msgM[w][4 * q + 2 * h2][c] = sig_f(p0) * sp_f(p1);
            msgM[w][4 * q + 2 * h2 + 1][c] = sig_f(p2) * sp_f(p3);
        }

        __builtin_amdgcn_wave_barrier();

        // wave-private paired segmented scan: lane -> (dd = lane&15, edges (lane>>4)*8..+8)
        {
            int dd = lane & 15;
            int base = (lane >> 4) * 8;
            float4 ma = *(const float4*)&msgM[w][dd][base];
            float4 mb = *(const float4*)&msgM[w][dd][base + 4];
            const int* dr = &dsh[w][base];
            int4 da = *(const int4*)dr;
            int4 db = *(const int4*)(dr + 4);
            float m[8] = {ma.x, ma.y, ma.z, ma.w, mb.x, mb.y, mb.z, mb.w};
            int dn[8] = {da.x, da.y, da.z, da.w, db.x, db.y, db.z, db.w};
            float accum = m[0];
            int cur = dn[0];
#pragma unroll
            for (int j = 1; j < 8; ++j) {
                if (dn[j] != cur) {
                    unsafeAtomicAdd(&agg[(unsigned)((cur << 6) + (w << 4) + dd)], accum);
                    accum = 0.0f;
                    cur = dn[j];
                }
                accum += m[j];
            }
            unsafeAtomicAdd(&agg[(unsigned)((cur << 6) + (w << 4) + dd)], accum);
        }
        __builtin_amdgcn_wave_barrier();
    }
}

// Unsorted fallback (only if ws too small for sort buffers): transposed MFMA,
// in-kernel eattr conversion, local gate pairing, direct atomics.
__global__ __launch_bounds__(256) void k_edge_u(
    const int* __restrict__ eidx, const float* __restrict__ eattr,
    const float* __restrict__ dstpack, const float* __restrict__ srcpack,
    const short* __restrict__ wcat_l, float* __restrict__ agg) {
    int tid = threadIdx.x;
    int w = tid >> 6;
    int lane = tid & 63;
    int c = lane & 31;
    int h2 = lane >> 5;

    short8v wfr[4];
#pragma unroll
    for (int kk = 0; kk < 4; ++kk) {
#pragma unroll
        for (int e = 0; e < 8; ++e) wfr[kk][e] = wcat_l[(kk * 16 + 8 * h2 + e) * 128 + w * 32 + c];
    }

    for (int tile = blockIdx.x; tile < NTILES; tile += gridDim.x) {
        int e0 = tile * 32;
        int myedge = e0 + c;
        int tI = eidx[N_EDGES + myedge];
        int sI = eidx[myedge];

        short8v efr[4];
        const float* erow = eattr + (size_t)myedge * EDIM;
#pragma unroll
        for (int kk = 0; kk < 3; ++kk) {
            int k0 = kk * 16 + 8 * h2;
#pragma unroll
            for (int p = 0; p < 4; ++p) {
                float2 v = *(const float2*)(erow + k0 + 2 * p);
                efr[kk][2 * p] = cvt_bf16(v.x);
                efr[kk][2 * p + 1] = cvt_bf16(v.y);
            }
        }
        {
            short8v a;
#pragma unroll
            for (int e = 0; e < 8; ++e) a[e] = 0;
            if (h2 == 0) {
                float2 v = *(const float2*)(erow + 48);
                a[0] = cvt_bf16(v.x);
                a[1] = cvt_bf16(v.y);
            }
            efr[3] = a;
        }
        f32x16 acc;
#pragma unroll
        for (int i = 0; i < 16; ++i) acc[i] = 0.0f;
#pragma unroll
        for (int kk = 0; kk < 4; ++kk)
            acc = __builtin_amdgcn_mfma_f32_32x32x16_bf16(wfr[kk], efr[kk], acc, 0, 0, 0);

        const float* drow = dstpack + (((size_t)(unsigned)tI) << 7) + w * 32 + 4 * h2;
        const float* srow = srcpack + (((size_t)(unsigned)sI) << 7) + w * 32 + 4 * h2;
#pragma unroll
        for (int q = 0; q < 4; ++q) {
            float4 dv = *(const float4*)(drow + 8 * q);
            float4 sv = *(const float4*)(srow + 8 * q);
            float p0 = acc[4 * q + 0] + dv.x + sv.x;
            float p1 = acc[4 * q + 1] + dv.y + sv.y;
            float p2 = acc[4 * q + 2] + dv.z + sv.z;
            float p3 = acc[4 * q + 3] + dv.w + sv.w;
            int dd = (w << 4) + 4 * q + 2 * h2;
            unsafeAtomicAdd(&agg[(unsigned)((tI << 6) + dd)], sig_f(p0) * sp_f(p1));
            unsafeAtomicAdd(&agg[(unsigned)((tI << 6) + dd + 1)], sig_f(p2) * sp_f(p3));
        }
    }
}

// Fused final update + sorted-batch pool: val = softplus(h+agg), run-length
// accumulate, one atomic per graph transition. agg left dirty (re-memset next call).
__global__ __launch_bounds__(256) void k_pool_s(
    const float* __restrict__ h, const float* __restrict__ agg,
    const int* __restrict__ batch,
    float* __restrict__ pooled, float* __restrict__ counts) {
    int tid = threadIdx.x;
    int d = tid & 63;
    int strm = tid >> 6;
    int base = blockIdx.x * 256 + strm * 64;
    if (base >= N_NODES) return;
    int end = min(base + 64, N_NODES);
    float accum = 0.0f;
    int cnt = 0;
    int cur = batch[base];
    for (int n = base; n < end; ++n) {
        int g = batch[n];
        if (g != cur) {
            unsafeAtomicAdd(&pooled[cur * DIM + d], accum);
            if (d == 0) unsafeAtomicAdd(&counts[cur], (float)cnt);
            accum = 0.0f;
            cnt = 0;
            cur = g;
        }
        accum += softplus_f(h[(size_t)n * DIM + d] + agg[(size_t)n * DIM + d]);
        cnt++;
    }
    unsafeAtomicAdd(&pooled[cur * DIM + d], accum);
    if (d == 0) unsafeAtomicAdd(&counts[cur], (float)cnt);
}

__global__ __launch_bounds__(64) void k_mlp(
    const float* __restrict__ pooled, const float* __restrict__ counts,
    const float* __restrict__ W1, const float* __restrict__ b1,
    const float* __restrict__ W2, const float* __restrict__ b2,
    const float* __restrict__ Wo, const float* __restrict__ bo,
    float* __restrict__ out) {
    __shared__ float ps[64];
    __shared__ float h1[128];
    int g = blockIdx.x, lane = threadIdx.x;
    float cnt = fmaxf(counts[g], 1.0f);
    ps[lane] = pooled[g * DIM + lane] / cnt;
    __syncthreads();
#pragma unroll
    for (int rep = 0; rep < 2; ++rep) {
        int j = lane + rep * 64;
        float acc = b1[j];
        for (int k = 0; k < 64; ++k) acc += ps[k] * W1[k * HDIM + j];
        h1[j] = fmaxf(acc, 0.0f);
    }
    __syncthreads();
    float acc = b2[lane];
    for (int k = 0; k < 128; ++k) acc += h1[k] * W2[k * 64 + lane];
    float v = fmaxf(acc, 0.0f) * Wo[lane];
#pragma unroll
    for (int off = 32; off; off >>= 1) v += __shfl_down(v, off);
    if (lane == 0) out[g] = v + bo[0];
}

extern "C" void kernel_launch(void* const* d_in, const int* in_sizes, int n_in,
                              void* d_out, int out_size, void* d_ws, size_t ws_size,
                              hipStream_t stream) {
    const int* x = (const int*)d_in[0];
    const int* eidx = (const int*)d_in[1];
    const float* eattr = (const float*)d_in[2];
    const int* batch = (const int*)d_in[3];
    const float* emb = (const float*)d_in[4];
    const float* Wf = (const float*)d_in[5];
    const float* bf = (const float*)d_in[6];
    const float* Ws = (const float*)d_in[7];
    const float* bs = (const float*)d_in[8];
    const float* W1 = (const float*)d_in[9];
    const float* b1 = (const float*)d_in[10];
    const float* W2 = (const float*)d_in[11];
    const float* b2 = (const float*)d_in[12];
    const float* Wo = (const float*)d_in[13];
    const float* bo = (const float*)d_in[14];
    float* out = (float*)d_out;

    char* p = (char*)d_ws;
    float* h = (float*)p;       p += (size_t)N_NODES * DIM * 4;
    float* dstpack = (float*)p; p += (size_t)N_NODES * 2 * DIM * 4;
    float* srcpack = (float*)p; p += (size_t)N_NODES * 2 * DIM * 4;
    float* agg = (float*)p;     p += (size_t)N_NODES * DIM * 4;
    float* pooled = (float*)p;  p += (size_t)N_GRAPHS * DIM * 4;
    float* counts = (float*)p;  p += (size_t)N_GRAPHS * 4;
    short* wcat = (short*)p;    p += (size_t)NLAYER * 64 * 128 * 2;
    short* eattrP = (short*)p;  p += (size_t)NTILES * 4 * 64 * 8 * 2;  // 102.4 MB
    int* hist = (int*)p;        p += (size_t)N_NODES * 4;
    int* scanbuf = (int*)p;     p += (size_t)N_NODES * 4;
    int* blocksums = (int*)p;   p += 256 * 4;
    int* cursor = (int*)p;      p += (size_t)N_NODES * 4;
    int* perm = (int*)p;        p += (size_t)N_EDGES * 4;
    int* permSrc = (int*)p;     p += (size_t)N_EDGES * 4;
    int* permDst = (int*)p;     p += (size_t)N_EDGES * 4;
    size_t used_sorted = (size_t)(p - (char*)d_ws);

    bool sorted = used_sorted <= ws_size;

    const int SCAN_BLOCKS = (N_NODES + 255) / 256;  // 196
    const int NODEMM_BLOCKS = (N_NODES + 63) / 64;  // 782

    k_wcat<<<NLAYER * 64 * 128 / 256, 256, 0, stream>>>(Wf, Ws, wcat);
    if (sorted) {
        hipMemsetAsync(hist, 0, (size_t)N_NODES * 4, stream);
        k_hist<<<N_EDGES / 256, 256, 0, stream>>>(eidx, hist);
        k_scan1<<<SCAN_BLOCKS, 256, 0, stream>>>(hist, scanbuf, blocksums);
        k_scan2<<<1, 256, 0, stream>>>(blocksums, SCAN_BLOCKS);
        k_scan3<<<SCAN_BLOCKS, 256, 0, stream>>>(scanbuf, hist, blocksums, cursor);
        k_scatter<<<N_EDGES / 256, 256, 0, stream>>>(eidx, cursor, perm, permSrc, permDst);
        k_eprep2<<<NTILES * 64 / 256, 256, 0, stream>>>(eattr, perm, eattrP);
    }
    hipMemsetAsync(agg, 0, (size_t)N_NODES * DIM * 4, stream);
    for (int l = 0; l < NLAYER; ++l) {
        const float* Wfl = Wf + (size_t)l * ZDIM * DIM;
        const float* Wsl = Ws + (size_t)l * ZDIM * DIM;
        if (l == 0) {
            k_nodemm<2><<<NODEMM_BLOCKS, 256, 0, stream>>>(
                nullptr, h, nullptr, x, emb, Wfl, bf + l * DIM, Wsl, bs + l * DIM,
                dstpack, srcpack);
        } else {
            k_nodemm<1><<<NODEMM_BLOCKS, 256, 0, stream>>>(
                h, h, agg, nullptr, nullptr, Wfl, bf + l * DIM, Wsl, bs + l * DIM,
                dstpack, srcpack);
        }
        if (sorted) {
            k_edge_s<<<2048, 256, 0, stream>>>(permSrc, permDst, eattrP, dstpack, srcpack,
                                               wcat + (size_t)l * 64 * 128, agg);
        } else {
            k_edge_u<<<2048, 256, 0, stream>>>(eidx, eattr, dstpack, srcpack,
                                               wcat + (size_t)l * 64 * 128, agg);
        }
    }
    hipMemsetAsync(pooled, 0, ((size_t)N_GRAPHS * DIM + N_GRAPHS) * 4, stream);
    k_pool_s<<<(N_NODES + 255) / 256, 256, 0, stream>>>(h, agg, batch, pooled, counts);
    k_mlp<<<N_GRAPHS, 64, 0, stream>>>(pooled, counts, W1, b1, W2, b2, Wo, bo, out);
}

// Round 10
// 906.682 us; speedup vs baseline: 1.0911x; 1.0911x over previous
//
#include <hip/hip_runtime.h>
#include <hip/hip_bf16.h>
#include <math.h>

#define N_NODES 50000
#define N_EDGES 800000
#define N_GRAPHS 256
#define DIM 64
#define EDIM 50
#define HDIM 128
#define NLAYER 4
#define ZDIM (2 * DIM + EDIM)  // 178
#define NTILES (N_EDGES / 32)  // 25000

typedef __attribute__((ext_vector_type(8))) short short8v;
typedef __attribute__((ext_vector_type(16))) float f32x16;

__device__ __forceinline__ float softplus_f(float x) {
    return fmaxf(x, 0.0f) + log1pf(__expf(-fabsf(x)));
}

__device__ __forceinline__ short cvt_bf16(float f) {
    __hip_bfloat16 h = __float2bfloat16(f);
    return *reinterpret_cast<short*>(&h);
}

// Weight tiles, column layout colv = g*64 + d (g: 0=sigmoid/Wf, 1=softplus/Ws)
// wcat[l][k][colv] = (k<50) ? W_g[l][128+k][d] : 0   (k padded to 64)
__global__ void k_wcat(const float* __restrict__ Wf, const float* __restrict__ Ws,
                       short* __restrict__ wcat) {
    int i = blockIdx.x * 256 + threadIdx.x;  // 4*64*128 = 32768
    int l = i >> 13;
    int rem = i & 8191;
    int k = rem >> 7;
    int colv = rem & 127;
    int g = colv >> 6, d = colv & 63;
    float v = 0.0f;
    if (k < 50) {
        const float* W = g ? Ws : Wf;
        v = W[((size_t)l * ZDIM + 128 + k) * 64 + d];
    }
    wcat[i] = cvt_bf16(v);
}

// ---------------- dst-sort (counting sort) ----------------
__global__ void k_hist(const int* __restrict__ eidx, int* __restrict__ hist) {
    int e = blockIdx.x * 256 + threadIdx.x;  // E exact
    atomicAdd(&hist[eidx[N_EDGES + e]], 1);
}

__global__ __launch_bounds__(256) void k_scan1(const int* __restrict__ hist,
                                               int* __restrict__ scanbuf,
                                               int* __restrict__ blocksums) {
    int tid = threadIdx.x;
    int i = blockIdx.x * 256 + tid;
    int v = (i < N_NODES) ? hist[i] : 0;
    int lane = tid & 63;
#pragma unroll
    for (int off = 1; off < 64; off <<= 1) {
        int u = __shfl_up(v, off);
        if (lane >= off) v += u;
    }
    __shared__ int wsum[4];
    if (lane == 63) wsum[tid >> 6] = v;
    __syncthreads();
    int w = tid >> 6;
    int add = 0;
#pragma unroll
    for (int k = 0; k < 3; ++k)
        if (k < w) add += wsum[k];
    v += add;
    if (i < N_NODES) scanbuf[i] = v;
    if (tid == 255) blocksums[blockIdx.x] = v;
}

__global__ __launch_bounds__(256) void k_scan2(int* __restrict__ blocksums, int nb) {
    int tid = threadIdx.x;
    int v = (tid < nb) ? blocksums[tid] : 0;
    int lane = tid & 63;
#pragma unroll
    for (int off = 1; off < 64; off <<= 1) {
        int u = __shfl_up(v, off);
        if (lane >= off) v += u;
    }
    __shared__ int wsum[4];
    if (lane == 63) wsum[tid >> 6] = v;
    __syncthreads();
    int w = tid >> 6;
    int add = 0;
#pragma unroll
    for (int k = 0; k < 3; ++k)
        if (k < w) add += wsum[k];
    v += add;
    if (tid < nb) blocksums[tid] = v;
}

__global__ void k_scan3(const int* __restrict__ scanbuf, const int* __restrict__ hist,
                        const int* __restrict__ blocksums, int* __restrict__ cursor) {
    int i = blockIdx.x * 256 + threadIdx.x;
    if (i >= N_NODES) return;
    int b = blockIdx.x;
    int off = b ? blocksums[b - 1] : 0;
    cursor[i] = scanbuf[i] - hist[i] + off;
}

__global__ void k_scatter(const int* __restrict__ eidx, int* __restrict__ cursor,
                          int* __restrict__ perm, int* __restrict__ permSrc,
                          int* __restrict__ permDst) {
    int e = blockIdx.x * 256 + threadIdx.x;
    int d = eidx[N_EDGES + e];
    int pos = atomicAdd(&cursor[d], 1);
    perm[pos] = e;
    permDst[pos] = d;
    permSrc[pos] = eidx[e];
}

// Sorted pack: thread = (tile, lane); handles all 4 kk fragments.
__global__ __launch_bounds__(256) void k_eprep2(const float* __restrict__ eattr,
                                                const int* __restrict__ perm,
                                                short* __restrict__ eattrP) {
    int i = blockIdx.x * 256 + threadIdx.x;  // over NTILES*64 = 1.6M
    int lane = i & 63;
    int tile = i >> 6;
    int pos = tile * 32 + (lane & 31);
    int h2 = lane >> 5;
    int edge = perm[pos];
    const float* erow = eattr + (size_t)edge * EDIM;  // 8B-aligned (200*edge)
    int k0 = 8 * h2;
    float2 v[12];
#pragma unroll
    for (int kk = 0; kk < 3; ++kk) {
#pragma unroll
        for (int p = 0; p < 4; ++p) {
            v[kk * 4 + p] = *(const float2*)(erow + k0 + 16 * kk + 2 * p);
        }
    }
    float2 t48 = make_float2(0.0f, 0.0f);
    if (h2 == 0) t48 = *(const float2*)(erow + 48);

    size_t fb = ((size_t)tile * 4) * 64 + lane;
#pragma unroll
    for (int kk = 0; kk < 3; ++kk) {
        short8v o;
#pragma unroll
        for (int p = 0; p < 4; ++p) {
            o[2 * p] = cvt_bf16(v[kk * 4 + p].x);
            o[2 * p + 1] = cvt_bf16(v[kk * 4 + p].y);
        }
        *(short8v*)&eattrP[(fb + (size_t)kk * 64) * 8] = o;
    }
    short8v o;
#pragma unroll
    for (int e = 0; e < 8; ++e) o[e] = 0;
    o[0] = cvt_bf16(t48.x);
    o[1] = cvt_bf16(t48.y);
    *(short8v*)&eattrP[(fb + 3 * 64) * 8] = o;
}

// Node-side matmuls, output layout [n][colv], colv = g*64+d.
// MODE 0: read h.  MODE 1: v=softplus(h+agg), write h, zero agg (fused update).
// MODE 2: v=emb[x[n]], write h (fused embed).
template <int MODE>
__global__ __launch_bounds__(256) void k_nodemm(
    const float* __restrict__ hin, float* __restrict__ hout, float* __restrict__ agg,
    const int* __restrict__ x, const float* __restrict__ emb,
    const float* __restrict__ Wf, const float* __restrict__ bf,
    const float* __restrict__ Ws, const float* __restrict__ bs,
    float* __restrict__ dstpack, float* __restrict__ srcpack) {
    __shared__ float hs[64 * 68];
    int tid = threadIdx.x;
    int w = tid >> 6, lane = tid & 63;
    int n0 = blockIdx.x * 64;
    for (int idx = tid; idx < 64 * 64; idx += 256) {
        int i = idx >> 6, k = idx & 63;
        int n = n0 + i;
        float v = 0.0f;
        if (n < N_NODES) {
            if (MODE == 0) {
                v = hin[(size_t)n * DIM + k];
            } else if (MODE == 1) {
                v = softplus_f(hin[(size_t)n * DIM + k] + agg[(size_t)n * DIM + k]);
                agg[(size_t)n * DIM + k] = 0.0f;
                hout[(size_t)n * DIM + k] = v;
            } else {
                v = emb[x[n] * DIM + k];
                hout[(size_t)n * DIM + k] = v;
            }
        }
        hs[i * 68 + k] = v;
    }
    __syncthreads();
    const float* Wsel = (w & 1) ? Ws : Wf;
    int row0 = (w < 2) ? 0 : 64;
    float wcol[64];
#pragma unroll
    for (int k = 0; k < 64; ++k) wcol[k] = Wsel[(row0 + k) * 64 + lane];
    float bias = (w == 0) ? bf[lane] : (w == 1) ? bs[lane] : 0.0f;
    float* outp = (w < 2) ? dstpack : srcpack;
    int colv = (w & 1) * 64 + lane;
    int nmax = min(64, N_NODES - n0);
    for (int i = 0; i < nmax; ++i) {
        float acc = bias;
#pragma unroll
        for (int k = 0; k < 64; k += 4) {
            float4 hv = *(const float4*)&hs[i * 68 + k];
            acc += hv.x * wcol[k] + hv.y * wcol[k + 1] + hv.z * wcol[k + 2] + hv.w * wcol[k + 3];
        }
        outp[(size_t)(n0 + i) * 128 + colv] = acc;
    }
}

// ---------------- sorted edge kernel (round-8 structure + depth-1 prefetch) ----------------
// Transposed MFMA: D[feat][edge], lane owns ONE edge (c = lane&31).
// waves 0,1 -> feats 0..63 (sigmoid); waves 2,3 -> feats 64..127 (softplus).
__global__ __launch_bounds__(256) void k_edge_s(
    const int* __restrict__ permSrc, const int* __restrict__ permDst,
    const short* __restrict__ eattrP, const float* __restrict__ dstpack,
    const float* __restrict__ srcpack, const short* __restrict__ wcat_l,
    float* __restrict__ agg) {
    __shared__ float msgV[2][64][34];  // [gate][d][edge], pitch 34
    __shared__ int dsh[32];
    int tid = threadIdx.x;
    int w = tid >> 6;
    int lane = tid & 63;
    int c = lane & 31;   // edge within tile
    int h2 = lane >> 5;
    int col = w * 32 + c;  // feature colv for the weight A-fragment

    // Weight A-fragments
    short8v wfr[4];
#pragma unroll
    for (int kk = 0; kk < 4; ++kk) {
#pragma unroll
        for (int e = 0; e < 8; ++e) {
            wfr[kk][e] = wcat_l[(kk * 16 + 8 * h2 + e) * 128 + col];
        }
    }

    // prologue: load tile 0's indices + fragments
    int tile = blockIdx.x;
    int tI = permDst[tile * 32 + c];
    int sI = permSrc[tile * 32 + c];
    short8v efr[4];
#pragma unroll
    for (int kk = 0; kk < 4; ++kk) {
        efr[kk] = *(const short8v*)&eattrP[(((size_t)tile * 4 + kk) * 64 + lane) * 8];
    }

    while (true) {
        if (tid < 32) dsh[tid] = tI;  // wave 0: c == tid

        // depth-1 prefetch of next tile (issues before MFMA; completes during epilogue)
        int nt = tile + gridDim.x;
        bool havenext = nt < NTILES;
        int tIn = tI, sIn = sI;
        short8v efn[4];
        if (havenext) {
            tIn = permDst[nt * 32 + c];
            sIn = permSrc[nt * 32 + c];
#pragma unroll
            for (int kk = 0; kk < 4; ++kk) {
                efn[kk] = *(const short8v*)&eattrP[(((size_t)nt * 4 + kk) * 64 + lane) * 8];
            }
        } else {
#pragma unroll
            for (int kk = 0; kk < 4; ++kk) efn[kk] = efr[kk];
        }

        f32x16 acc;
#pragma unroll
        for (int i = 0; i < 16; ++i) acc[i] = 0.0f;
#pragma unroll
        for (int kk = 0; kk < 4; ++kk) {
            acc = __builtin_amdgcn_mfma_f32_32x32x16_bf16(wfr[kk], efr[kk], acc, 0, 0, 0);
        }

        // Gathers: one row each from dstpack/srcpack, 4 dwordx4 per table
        const float* drow = dstpack + (((size_t)(unsigned)tI) << 7) + w * 32 + 4 * h2;
        const float* srow = srcpack + (((size_t)(unsigned)sI) << 7) + w * 32 + 4 * h2;
        float4 dv[4], sv[4];
#pragma unroll
        for (int q = 0; q < 4; ++q) dv[q] = *(const float4*)(drow + 8 * q);
#pragma unroll
        for (int q = 0; q < 4; ++q) sv[q] = *(const float4*)(srow + 8 * q);

        int dbase = (w & 1) * 32 + 4 * h2;  // d = dbase + 8*q + i
        if (w < 2) {  // sigmoid, gate 0
#pragma unroll
            for (int q = 0; q < 4; ++q) {
#pragma unroll
                for (int i = 0; i < 4; ++i) {
                    float pre = acc[4 * q + i] + dv[q][i] + sv[q][i];
                    float e = __expf(-fabsf(pre));
                    float inv = __builtin_amdgcn_rcpf(1.0f + e);
                    msgV[0][dbase + 8 * q + i][c] = (pre >= 0.0f) ? inv : e * inv;
                }
            }
        } else {  // softplus, gate 1
#pragma unroll
            for (int q = 0; q < 4; ++q) {
#pragma unroll
                for (int i = 0; i < 4; ++i) {
                    float pre = acc[4 * q + i] + dv[q][i] + sv[q][i];
                    float e = __expf(-fabsf(pre));
                    msgV[1][dbase + 8 * q + i][c] = fmaxf(pre, 0.0f) + __logf(1.0f + e);
                }
            }
        }

        __syncthreads();

        // paired segmented scan: thread -> (d = tid&63, edges (tid>>6)*8 .. +8)
        {
            int d = tid & 63;
            int base = (tid >> 6) * 8;
            float m[8];
#pragma unroll
            for (int j2 = 0; j2 < 4; ++j2) {
                float2 a = *(const float2*)&msgV[0][d][base + 2 * j2];
                float2 b = *(const float2*)&msgV[1][d][base + 2 * j2];
                m[2 * j2] = a.x * b.x;
                m[2 * j2 + 1] = a.y * b.y;
            }
            float accum = 0.0f;
            int cur = dsh[base];
#pragma unroll
            for (int j = 0; j < 8; ++j) {
                int dn = dsh[base + j];
                if (dn != cur) {
                    unsafeAtomicAdd(&agg[(unsigned)((cur << 6) + d)], accum);
                    accum = 0.0f;
                    cur = dn;
                }
                accum += m[j];
            }
            unsafeAtomicAdd(&agg[(unsigned)((cur << 6) + d)], accum);
        }
        __syncthreads();

        if (!havenext) break;
        tile = nt;
        tI = tIn;
        sI = sIn;
#pragma unroll
        for (int kk = 0; kk < 4; ++kk) efr[kk] = efn[kk];
    }
}

// Unsorted fallback (only if ws too small for sort buffers).
__global__ __launch_bounds__(256) void k_edge_u(
    const int* __restrict__ eidx, const float* __restrict__ eattr,
    const float* __restrict__ dstpack, const float* __restrict__ srcpack,
    const short* __restrict__ wcat_l, float* __restrict__ agg) {
    __shared__ float msgV[2][32][64];
    __shared__ int dsh[32], ssh[32];
    int tid = threadIdx.x;
    int w = tid >> 6;
    int lane = tid & 63;
    int c = lane & 31;
    int h2 = lane >> 5;
    int col = w * 32 + c;
    int dcol = (w & 1) * 32 + c;

    short8v bfr[4];
#pragma unroll
    for (int kk = 0; kk < 4; ++kk) {
#pragma unroll
        for (int e = 0; e < 8; ++e) bfr[kk][e] = wcat_l[(kk * 16 + 8 * h2 + e) * 128 + col];
    }

    for (int tile = blockIdx.x; tile < NTILES; tile += gridDim.x) {
        int e0 = tile * 32;
        if (lane < 32) {
            dsh[lane] = eidx[N_EDGES + e0 + lane];
            ssh[lane] = eidx[e0 + lane];
        }
        short8v afr[4];
        const float* erow = eattr + (size_t)(e0 + c) * EDIM;
#pragma unroll
        for (int kk = 0; kk < 3; ++kk) {
            int k0 = kk * 16 + 8 * h2;
#pragma unroll
            for (int p = 0; p < 4; ++p) {
                float2 v = *(const float2*)(erow + k0 + 2 * p);
                afr[kk][2 * p] = cvt_bf16(v.x);
                afr[kk][2 * p + 1] = cvt_bf16(v.y);
            }
        }
        {
            short8v a;
#pragma unroll
            for (int e = 0; e < 8; ++e) a[e] = 0;
            if (h2 == 0) {
                float2 v = *(const float2*)(erow + 48);
                a[0] = cvt_bf16(v.x);
                a[1] = cvt_bf16(v.y);
            }
            afr[3] = a;
        }
        f32x16 acc;
#pragma unroll
        for (int i = 0; i < 16; ++i) acc[i] = 0.0f;
#pragma unroll
        for (int kk = 0; kk < 4; ++kk)
            acc = __builtin_amdgcn_mfma_f32_32x32x16_bf16(afr[kk], bfr[kk], acc, 0, 0, 0);

        __builtin_amdgcn_wave_barrier();

#pragma unroll
        for (int grp = 0; grp < 2; ++grp) {
            int tI[8], sI[8];
            float dv[8], sv[8];
#pragma unroll
            for (int r = 0; r < 8; ++r) {
                int rr = grp * 8 + r;
                int row = (rr & 3) + 8 * (rr >> 2) + 4 * h2;
                tI[r] = dsh[row];
                sI[r] = ssh[row];
            }
#pragma unroll
            for (int r = 0; r < 8; ++r) {
                dv[r] = dstpack[(unsigned)((tI[r] << 7) + col)];
                sv[r] = srcpack[(unsigned)((sI[r] << 7) + col)];
            }
            float pre[8];
#pragma unroll
            for (int r = 0; r < 8; ++r) pre[r] = acc[grp * 8 + r] + dv[r] + sv[r];
            if (w < 2) {
#pragma unroll
                for (int r = 0; r < 8; ++r) {
                    int rr = grp * 8 + r;
                    int row = (rr & 3) + 8 * (rr >> 2) + 4 * h2;
                    float e = __expf(-fabsf(pre[r]));
                    float inv = __builtin_amdgcn_rcpf(1.0f + e);
                    msgV[0][row][dcol] = (pre[r] >= 0.0f) ? inv : e * inv;
                }
            } else {
#pragma unroll
                for (int r = 0; r < 8; ++r) {
                    int rr = grp * 8 + r;
                    int row = (rr & 3) + 8 * (rr >> 2) + 4 * h2;
                    float e = __expf(-fabsf(pre[r]));
                    msgV[1][row][dcol] = fmaxf(pre[r], 0.0f) + __logf(1.0f + e);
                }
            }
        }
        __syncthreads();
        {
            int d = tid & 63;
            int base = (tid >> 6) * 8;
#pragma unroll
            for (int j = 0; j < 8; ++j) {
                int row = base + j;
                float m = msgV[0][row][d] * msgV[1][row][d];
                unsafeAtomicAdd(&agg[(unsigned)((dsh[row] << 6) + d)], m);
            }
        }
        __syncthreads();
    }
}

// Fused final update + sorted-batch pool: val = softplus(h+agg), run-length
// accumulate, one atomic per graph transition. agg left dirty (re-memset next call).
__global__ __launch_bounds__(256) void k_pool_s(
    const float* __restrict__ h, const float* __restrict__ agg,
    const int* __restrict__ batch,
    float* __restrict__ pooled, float* __restrict__ counts) {
    int tid = threadIdx.x;
    int d = tid & 63;
    int strm = tid >> 6;
    int base = blockIdx.x * 256 + strm * 64;
    if (base >= N_NODES) return;
    int end = min(base + 64, N_NODES);
    float accum = 0.0f;
    int cnt = 0;
    int cur = batch[base];
    for (int n = base; n < end; ++n) {
        int g = batch[n];
        if (g != cur) {
            unsafeAtomicAdd(&pooled[cur * DIM + d], accum);
            if (d == 0) unsafeAtomicAdd(&counts[cur], (float)cnt);
            accum = 0.0f;
            cnt = 0;
            cur = g;
        }
        accum += softplus_f(h[(size_t)n * DIM + d] + agg[(size_t)n * DIM + d]);
        cnt++;
    }
    unsafeAtomicAdd(&pooled[cur * DIM + d], accum);
    if (d == 0) unsafeAtomicAdd(&counts[cur], (float)cnt);
}

__global__ __launch_bounds__(64) void k_mlp(
    const float* __restrict__ pooled, const float* __restrict__ counts,
    const float* __restrict__ W1, const float* __restrict__ b1,
    const float* __restrict__ W2, const float* __restrict__ b2,
    const float* __restrict__ Wo, const float* __restrict__ bo,
    float* __restrict__ out) {
    __shared__ float ps[64];
    __shared__ float h1[128];
    int g = blockIdx.x, lane = threadIdx.x;
    float cnt = fmaxf(counts[g], 1.0f);
    ps[lane] = pooled[g * DIM + lane] / cnt;
    __syncthreads();
#pragma unroll
    for (int rep = 0; rep < 2; ++rep) {
        int j = lane + rep * 64;
        float acc = b1[j];
        for (int k = 0; k < 64; ++k) acc += ps[k] * W1[k * HDIM + j];
        h1[j] = fmaxf(acc, 0.0f);
    }
    __syncthreads();
    float acc = b2[lane];
    for (int k = 0; k < 128; ++k) acc += h1[k] * W2[k * 64 + lane];
    float v = fmaxf(acc, 0.0f) * Wo[lane];
#pragma unroll
    for (int off = 32; off; off >>= 1) v += __shfl_down(v, off);
    if (lane == 0) out[g] = v + bo[0];
}

extern "C" void kernel_launch(void* const* d_in, const int* in_sizes, int n_in,
                              void* d_out, int out_size, void* d_ws, size_t ws_size,
                              hipStream_t stream) {
    const int* x = (const int*)d_in[0];
    const int* eidx = (const int*)d_in[1];
    const float* eattr = (const float*)d_in[2];
    const int* batch = (const int*)d_in[3];
    const float* emb = (const float*)d_in[4];
    const float* Wf = (const float*)d_in[5];
    const float* bf = (const float*)d_in[6];
    const float* Ws = (const float*)d_in[7];
    const float* bs = (const float*)d_in[8];
    const float* W1 = (const float*)d_in[9];
    const float* b1 = (const float*)d_in[10];
    const float* W2 = (const float*)d_in[11];
    const float* b2 = (const float*)d_in[12];
    const float* Wo = (const float*)d_in[13];
    const float* bo = (const float*)d_in[14];
    float* out = (float*)d_out;

    char* p = (char*)d_ws;
    float* h = (float*)p;       p += (size_t)N_NODES * DIM * 4;
    float* dstpack = (float*)p; p += (size_t)N_NODES * 2 * DIM * 4;
    float* srcpack = (float*)p; p += (size_t)N_NODES * 2 * DIM * 4;
    float* agg = (float*)p;     p += (size_t)N_NODES * DIM * 4;
    float* pooled = (float*)p;  p += (size_t)N_GRAPHS * DIM * 4;
    float* counts = (float*)p;  p += (size_t)N_GRAPHS * 4;
    short* wcat = (short*)p;    p += (size_t)NLAYER * 64 * 128 * 2;
    short* eattrP = (short*)p;  p += (size_t)NTILES * 4 * 64 * 8 * 2;  // 102.4 MB
    int* hist = (int*)p;        p += (size_t)N_NODES * 4;
    int* scanbuf = (int*)p;     p += (size_t)N_NODES * 4;
    int* blocksums = (int*)p;   p += 256 * 4;
    int* cursor = (int*)p;      p += (size_t)N_NODES * 4;
    int* perm = (int*)p;        p += (size_t)N_EDGES * 4;
    int* permSrc = (int*)p;     p += (size_t)N_EDGES * 4;
    int* permDst = (int*)p;     p += (size_t)N_EDGES * 4;
    size_t used_sorted = (size_t)(p - (char*)d_ws);

    bool sorted = used_sorted <= ws_size;

    const int SCAN_BLOCKS = (N_NODES + 255) / 256;  // 196
    const int NODEMM_BLOCKS = (N_NODES + 63) / 64;  // 782

    k_wcat<<<NLAYER * 64 * 128 / 256, 256, 0, stream>>>(Wf, Ws, wcat);
    if (sorted) {
        hipMemsetAsync(hist, 0, (size_t)N_NODES * 4, stream);
        k_hist<<<N_EDGES / 256, 256, 0, stream>>>(eidx, hist);
        k_scan1<<<SCAN_BLOCKS, 256, 0, stream>>>(hist, scanbuf, blocksums);
        k_scan2<<<1, 256, 0, stream>>>(blocksums, SCAN_BLOCKS);
        k_scan3<<<SCAN_BLOCKS, 256, 0, stream>>>(scanbuf, hist, blocksums, cursor);
        k_scatter<<<N_EDGES / 256, 256, 0, stream>>>(eidx, cursor, perm, permSrc, permDst);
        k_eprep2<<<NTILES * 64 / 256, 256, 0, stream>>>(eattr, perm, eattrP);
    }
    hipMemsetAsync(agg, 0, (size_t)N_NODES * DIM * 4, stream);
    for (int l = 0; l < NLAYER; ++l) {
        const float* Wfl = Wf + (size_t)l * ZDIM * DIM;
        const float* Wsl = Ws + (size_t)l * ZDIM * DIM;
        if (l == 0) {
            k_nodemm<2><<<NODEMM_BLOCKS, 256, 0, stream>>>(
                nullptr, h, nullptr, x, emb, Wfl, bf + l * DIM, Wsl, bs + l * DIM,
                dstpack, srcpack);
        } else {
            k_nodemm<1><<<NODEMM_BLOCKS, 256, 0, stream>>>(
                h, h, agg, nullptr, nullptr, Wfl, bf + l * DIM, Wsl, bs + l * DIM,
                dstpack, srcpack);
        }
        if (sorted) {
            k_edge_s<<<2048, 256, 0, stream>>>(permSrc, permDst, eattrP, dstpack, srcpack,
                                               wcat + (size_t)l * 64 * 128, agg);
        } else {
            k_edge_u<<<2048, 256, 0, stream>>>(eidx, eattr, dstpack, srcpack,
                                               wcat + (size_t)l * 64 * 128, agg);
        }
    }
    hipMemsetAsync(pooled, 0, ((size_t)N_GRAPHS * DIM + N_GRAPHS) * 4, stream);
    k_pool_s<<<(N_NODES + 255) / 256, 256, 0, stream>>>(h, agg, batch, pooled, counts);
    k_mlp<<<N_GRAPHS, 64, 0, stream>>>(pooled, counts, W1, b1, W2, b2, Wo, bo, out);
}